// Round 1
// baseline (209.292 us; speedup 1.0000x reference)
//
#include <hip/hip_runtime.h>

#define NVV   778
#define NSEG  16
#define SEGSZ 49
#define GRIDN 32
#define BATCH 128
#define NPTS  (NSEG * SEGSZ)   // 784

// Stage 1: per (side, b, j) compute box center (per-coord) and scale
// (0.55 * max extent). side 0 = right = vertices[:,0], side 1 = left.
__global__ __launch_bounds__(256) void boxes_kernel(
    const float* __restrict__ vertices, const int* __restrict__ seg,
    float* __restrict__ centers,   // [2][BATCH][NSEG][3]
    float* __restrict__ scales)    // [2][BATCH][NSEG]
{
    int t = blockIdx.x * blockDim.x + threadIdx.x;
    if (t >= 2 * BATCH * NSEG) return;
    int j    = t % NSEG;
    int b    = (t / NSEG) % BATCH;
    int side = t / (NSEG * BATCH);
    const float* vb = vertices + ((size_t)b * 2 + side) * NVV * 3;
    float mn0 = 1e30f, mn1 = 1e30f, mn2 = 1e30f;
    float mx0 = -1e30f, mx1 = -1e30f, mx2 = -1e30f;
    for (int s = 0; s < SEGSZ; ++s) {
        int vi = seg[j * SEGSZ + s];
        const float* v = vb + (size_t)vi * 3;
        float x = v[0], y = v[1], z = v[2];
        mn0 = fminf(mn0, x); mx0 = fmaxf(mx0, x);
        mn1 = fminf(mn1, y); mx1 = fmaxf(mx1, y);
        mn2 = fminf(mn2, z); mx2 = fmaxf(mx2, z);
    }
    int bi = (side * BATCH + b) * NSEG + j;
    centers[bi * 3 + 0] = 0.5f * (mn0 + mx0);
    centers[bi * 3 + 1] = 0.5f * (mn1 + mx1);
    centers[bi * 3 + 2] = 0.5f * (mn2 + mx2);
    float ext = fmaxf(fmaxf(mx0 - mn0, mx1 - mn1), mx2 - mn2);
    scales[bi] = 0.55f * ext;   // (1 + 0.1) * 0.5
}

// Stage 2: one block per (pass, b, k). pass 0: left verts sampled in
// phi_right with right boxes; pass 1: right verts in phi_left with left boxes.
// Sum all samples, atomicAdd(loss[b], sum * 0.25).
__global__ __launch_bounds__(256) void sample_kernel(
    const float* __restrict__ vertices, const int* __restrict__ seg,
    const float* __restrict__ phiR, const float* __restrict__ phiL,
    const float* __restrict__ centers, const float* __restrict__ scales,
    float* __restrict__ loss)
{
    int blk  = blockIdx.x;
    int k    = blk % NSEG;
    int b    = (blk / NSEG) % BATCH;
    int pass = blk / (NSEG * BATCH);
    int srcSide = (pass == 0) ? 1 : 0;   // pass0 samples LEFT vertices
    int boxSide = 1 - srcSide;           // using the OTHER side's boxes
    const float* phi = (pass == 0 ? phiR : phiL) +
                       ((size_t)k * BATCH + b) * (GRIDN * GRIDN * GRIDN);
    const float* vb = vertices + ((size_t)b * 2 + srcSide) * NVV * 3;
    int bi = (boxSide * BATCH + b) * NSEG + k;
    float cx = centers[bi * 3 + 0];
    float cy = centers[bi * 3 + 1];
    float cz = centers[bi * 3 + 2];
    float invs = 1.0f / scales[bi];

    float acc = 0.0f;
    for (int p = threadIdx.x; p < NPTS; p += 256) {
        int vi = seg[p];
        const float* v = vb + (size_t)vi * 3;
        float fx = ((v[0] - cx) * invs + 1.0f) * 15.5f;
        float fy = ((v[1] - cy) * invs + 1.0f) * 15.5f;
        float fz = ((v[2] - cz) * invs + 1.0f) * 15.5f;
        // fully-outside fast path: no taps can contribute
        if (fx <= -1.0f || fx >= 32.0f ||
            fy <= -1.0f || fy >= 32.0f ||
            fz <= -1.0f || fz >= 32.0f) continue;
        float x0f = floorf(fx), y0f = floorf(fy), z0f = floorf(fz);
        float wx = fx - x0f, wy = fy - y0f, wz = fz - z0f;
        int x0 = (int)x0f, y0 = (int)y0f, z0 = (int)z0f;
        #pragma unroll
        for (int dz = 0; dz < 2; ++dz) {
            int zz = z0 + dz;
            if (zz < 0 || zz >= GRIDN) continue;
            float wwz = dz ? wz : 1.0f - wz;
            #pragma unroll
            for (int dy = 0; dy < 2; ++dy) {
                int yy = y0 + dy;
                if (yy < 0 || yy >= GRIDN) continue;
                float wzy = wwz * (dy ? wy : 1.0f - wy);
                const float* row = phi + zz * (GRIDN * GRIDN) + yy * GRIDN;
                #pragma unroll
                for (int dx = 0; dx < 2; ++dx) {
                    int xx = x0 + dx;
                    if (xx < 0 || xx >= GRIDN) continue;
                    acc += wzy * (dx ? wx : 1.0f - wx) * row[xx];
                }
            }
        }
    }

    // block reduction: wave64 shfl then LDS across the 4 waves
    for (int off = 32; off > 0; off >>= 1)
        acc += __shfl_down(acc, off);
    __shared__ float wsum[4];
    int wid  = threadIdx.x >> 6;
    int lane = threadIdx.x & 63;
    if (lane == 0) wsum[wid] = acc;
    __syncthreads();
    if (threadIdx.x == 0) {
        float tot = wsum[0] + wsum[1] + wsum[2] + wsum[3];
        atomicAdd(loss + b, tot * 0.25f);
    }
}

extern "C" void kernel_launch(void* const* d_in, const int* in_sizes, int n_in,
                              void* d_out, int out_size, void* d_ws, size_t ws_size,
                              hipStream_t stream) {
    const float* vertices = (const float*)d_in[0];
    const float* phiR     = (const float*)d_in[1];
    const float* phiL     = (const float*)d_in[2];
    const int*   seg      = (const int*)d_in[3];
    float* loss = (float*)d_out;

    float* centers = (float*)d_ws;                       // 2*128*16*3 floats
    float* scales  = centers + 2 * BATCH * NSEG * 3;     // 2*128*16 floats

    hipMemsetAsync(d_out, 0, (size_t)out_size * sizeof(float), stream);

    boxes_kernel<<<(2 * BATCH * NSEG + 255) / 256, 256, 0, stream>>>(
        vertices, seg, centers, scales);

    sample_kernel<<<2 * BATCH * NSEG, 256, 0, stream>>>(
        vertices, seg, phiR, phiL, centers, scales, loss);
}

// Round 2
// 111.231 us; speedup vs baseline: 1.8816x; 1.8816x over previous
//
#include <hip/hip_runtime.h>

#define NVV   778
#define NSEG  16
#define SEGSZ 49
#define GRIDN 32
#define BATCH 128
#define NPTS  (NSEG * SEGSZ)   // 784
#define VOLSZ (GRIDN * GRIDN * GRIDN)  // 32768 floats = 128 KB

// One block per (pass, b, k). Stages the whole 128 KB volume phi[k,b] into
// LDS with coalesced float4 streams, computes the box (wave 0) in parallel,
// then does all 784 trilinear samples from LDS.
__global__ __launch_bounds__(1024) void sample_kernel(
    const float* __restrict__ vertices, const int* __restrict__ seg,
    const float* __restrict__ phiR, const float* __restrict__ phiL,
    float* __restrict__ loss)
{
    __shared__ float vol[VOLSZ];        // 128 KB
    __shared__ float wsum[16];
    __shared__ float sbox[4];           // cx, cy, cz, inv_scale

    int blk  = blockIdx.x;
    int k    = blk % NSEG;
    int b    = (blk / NSEG) % BATCH;
    int pass = blk / (NSEG * BATCH);
    int srcSide = (pass == 0) ? 1 : 0;   // pass0 samples LEFT vertices
    int boxSide = 1 - srcSide;           // with the OTHER side's boxes
    const float* phi = (pass == 0 ? phiR : phiL) +
                       ((size_t)k * BATCH + b) * VOLSZ;
    const float* vsrc = vertices + ((size_t)b * 2 + srcSide) * NVV * 3;
    const float* vbox = vertices + ((size_t)b * 2 + boxSide) * NVV * 3;

    const int tid = threadIdx.x;

    // ---- issue staging loads (8 x float4 per thread, coalesced) ----
    float4 stg[8];
    #pragma unroll
    for (int i = 0; i < 8; ++i)
        stg[i] = *(const float4*)(phi + ((i * 1024 + tid) << 2));

    // ---- box compute on wave 0 (overlaps staging latency) ----
    if (tid < 64) {
        bool act = tid < SEGSZ;
        int vi = act ? seg[k * SEGSZ + tid] : 0;
        const float* v = vbox + (size_t)vi * 3;
        float x = v[0], y = v[1], z = v[2];
        float mnx = act ? x : 1e30f, mxx = act ? x : -1e30f;
        float mny = act ? y : 1e30f, mxy = act ? y : -1e30f;
        float mnz = act ? z : 1e30f, mxz = act ? z : -1e30f;
        #pragma unroll
        for (int m = 32; m; m >>= 1) {
            mnx = fminf(mnx, __shfl_xor(mnx, m));
            mxx = fmaxf(mxx, __shfl_xor(mxx, m));
            mny = fminf(mny, __shfl_xor(mny, m));
            mxy = fmaxf(mxy, __shfl_xor(mxy, m));
            mnz = fminf(mnz, __shfl_xor(mnz, m));
            mxz = fmaxf(mxz, __shfl_xor(mxz, m));
        }
        if (tid == 0) {
            sbox[0] = 0.5f * (mnx + mxx);
            sbox[1] = 0.5f * (mny + mxy);
            sbox[2] = 0.5f * (mnz + mxz);
            float ext = fmaxf(fmaxf(mxx - mnx, mxy - mny), mxz - mnz);
            sbox[3] = 1.0f / (0.55f * ext);   // (1+0.1)*0.5 * ext
        }
    }

    // ---- point vertex loads (independent of box/staging) ----
    float vx = 0.f, vy = 0.f, vz = 0.f;
    if (tid < NPTS) {
        int vi = seg[tid];
        const float* v = vsrc + (size_t)vi * 3;
        vx = v[0]; vy = v[1]; vz = v[2];
    }

    // ---- commit staging to LDS ----
    #pragma unroll
    for (int i = 0; i < 8; ++i)
        *(float4*)&vol[(i * 1024 + tid) << 2] = stg[i];

    __syncthreads();

    // ---- trilinear taps from LDS ----
    float acc = 0.0f;
    if (tid < NPTS) {
        float cx = sbox[0], cy = sbox[1], cz = sbox[2], invs = sbox[3];
        float fx = ((vx - cx) * invs + 1.0f) * 15.5f;
        float fy = ((vy - cy) * invs + 1.0f) * 15.5f;
        float fz = ((vz - cz) * invs + 1.0f) * 15.5f;
        if (!(fx <= -1.0f || fx >= 32.0f ||
              fy <= -1.0f || fy >= 32.0f ||
              fz <= -1.0f || fz >= 32.0f)) {
            float x0f = floorf(fx), y0f = floorf(fy), z0f = floorf(fz);
            float wx = fx - x0f, wy = fy - y0f, wz = fz - z0f;
            int x0 = (int)x0f, y0 = (int)y0f, z0 = (int)z0f;
            #pragma unroll
            for (int dz = 0; dz < 2; ++dz) {
                int zz = z0 + dz;
                if (zz < 0 || zz >= GRIDN) continue;
                float wwz = dz ? wz : 1.0f - wz;
                #pragma unroll
                for (int dy = 0; dy < 2; ++dy) {
                    int yy = y0 + dy;
                    if (yy < 0 || yy >= GRIDN) continue;
                    float wzy = wwz * (dy ? wy : 1.0f - wy);
                    const float* row = vol + zz * (GRIDN * GRIDN) + yy * GRIDN;
                    #pragma unroll
                    for (int dx = 0; dx < 2; ++dx) {
                        int xx = x0 + dx;
                        if (xx < 0 || xx >= GRIDN) continue;
                        acc += wzy * (dx ? wx : 1.0f - wx) * row[xx];
                    }
                }
            }
        }
    }

    // ---- block reduction: wave shfl then LDS across 16 waves ----
    #pragma unroll
    for (int off = 32; off; off >>= 1)
        acc += __shfl_down(acc, off);
    int wid  = tid >> 6;
    int lane = tid & 63;
    if (lane == 0) wsum[wid] = acc;
    __syncthreads();
    if (tid == 0) {
        float tot = 0.f;
        #pragma unroll
        for (int i = 0; i < 16; ++i) tot += wsum[i];
        atomicAdd(loss + b, tot * 0.25f);
    }
}

extern "C" void kernel_launch(void* const* d_in, const int* in_sizes, int n_in,
                              void* d_out, int out_size, void* d_ws, size_t ws_size,
                              hipStream_t stream) {
    const float* vertices = (const float*)d_in[0];
    const float* phiR     = (const float*)d_in[1];
    const float* phiL     = (const float*)d_in[2];
    const int*   seg      = (const int*)d_in[3];
    float* loss = (float*)d_out;

    hipMemsetAsync(d_out, 0, (size_t)out_size * sizeof(float), stream);

    sample_kernel<<<2 * BATCH * NSEG, 1024, 0, stream>>>(
        vertices, seg, phiR, phiL, loss);
}